// Round 6
// baseline (276.719 us; speedup 1.0000x reference)
//
#include <hip/hip_runtime.h>

// x,y [N=4, C=64, H=128, W=256] fp32, maxdisp=48 (fixed by setup_inputs).
// out[n,i,h,w] = sum_c x[n,c,h,w] * y[n,c,h,w-i], zero where w-i<0.
#define N_ 4
#define C_ 64
#define H_ 128
#define W_ 256
#define D_ 48
#define HW_ (H_ * W_)

#define WTILE 128               // w-columns per block
#define HALO  D_                // 48-col left halo (zero-filled below w=0)
#define YCOLS (WTILE + HALO)    // 176 floats per staged y row
#define CCHUNK 16               // channels resident per LDS buffer
#define NCHUNK (C_ / CCHUNK)    // 4
#define VT 4                    // w-columns per thread
#define DT 12                   // disparities per thread
#define NTW (WTILE / VT)        // 32
#define NIG (D_ / DT)           // 4
#define NTHREADS (NTW * NIG)    // 128 = 2 waves
#define YF4 (CCHUNK * (YCOLS / 4))          // 704 float4 per chunk
#define NPREF ((YF4 + NTHREADS - 1) / NTHREADS)  // 6 staging iters

// LDS: 2 * 16 * 176 * 4 = 22528 B. Grid 1024 = 4 blocks/CU, 8 waves/CU.
__global__ __launch_bounds__(NTHREADS, 2)
void corr1d_v3(const float* __restrict__ x,
               const float* __restrict__ y,
               float* __restrict__ out) {
    __shared__ __align__(16) float ysh[2][CCHUNK][YCOLS];

    const int t  = threadIdx.x;
    const int tw = t & (NTW - 1);     // 0..31
    const int ig = t >> 5;            // 0..3 disparity group
    const int b  = blockIdx.x;
    const int wt = (b & 1) * WTILE;   // 0 or 128
    const int nh = b >> 1;
    const int n  = nh / H_;
    const int h  = nh % H_;

    const size_t in_base = ((size_t)n * C_ * H_ + h) * W_;
    const int i0 = ig * DT;
    const int w0 = wt + tw * VT;
    // window: ysh col j = 48 + 4*tw + v - 12*ig - k; aligned read start:
    const int js = 4 * tw - DT * ig + (HALO - DT);   // 0..160, %4==0; m=12+v-k in [1,15]

    float acc[DT][VT];
    #pragma unroll
    for (int k = 0; k < DT; ++k)
        #pragma unroll
        for (int v = 0; v < VT; ++v) acc[k][v] = 0.f;

    float4 yp[NPREF];

    // ---- prologue: stage y chunk 0 into buf 0 ----
    #pragma unroll
    for (int kk = 0; kk < NPREF; ++kk) {
        int idx = kk * NTHREADS + t;
        if (idx < YF4) {
            int r = idx / (YCOLS / 4);
            int q = idx % (YCOLS / 4);
            int w = wt - HALO + 4 * q;
            yp[kk] = (w >= 0)
                ? *reinterpret_cast<const float4*>(&y[in_base + (size_t)r * HW_ + w])
                : make_float4(0.f, 0.f, 0.f, 0.f);
        }
    }
    #pragma unroll
    for (int kk = 0; kk < NPREF; ++kk) {
        int idx = kk * NTHREADS + t;
        if (idx < YF4) {
            int r = idx / (YCOLS / 4);
            int q = idx % (YCOLS / 4);
            *reinterpret_cast<float4*>(&ysh[0][r][4 * q]) = yp[kk];
        }
    }
    __syncthreads();

    // x prefetch one c ahead (direct from global; L1 serves the repeat wave)
    float4 xn = *reinterpret_cast<const float4*>(&x[in_base + w0]);

    for (int ch = 0; ch < NCHUNK; ++ch) {
        const int cur = ch & 1;

        // issue global loads for next y chunk (lands during compute)
        if (ch + 1 < NCHUNK) {
            const int c0n = (ch + 1) * CCHUNK;
            #pragma unroll
            for (int kk = 0; kk < NPREF; ++kk) {
                int idx = kk * NTHREADS + t;
                if (idx < YF4) {
                    int r = idx / (YCOLS / 4);
                    int q = idx % (YCOLS / 4);
                    int w = wt - HALO + 4 * q;
                    yp[kk] = (w >= 0)
                        ? *reinterpret_cast<const float4*>(
                              &y[in_base + (size_t)(c0n + r) * HW_ + w])
                        : make_float4(0.f, 0.f, 0.f, 0.f);
                }
            }
        }

        // ---- compute on buf[cur] ----
        #pragma unroll
        for (int cc = 0; cc < CCHUNK; ++cc) {
            const float4 xq = xn;
            const int c = ch * CCHUNK + cc;
            if (c + 1 < C_)
                xn = *reinterpret_cast<const float4*>(
                    &x[in_base + (size_t)(c + 1) * HW_ + w0]);

            const float* yr = &ysh[cur][cc][js];
            const float4 q0 = *reinterpret_cast<const float4*>(yr);
            const float4 q1 = *reinterpret_cast<const float4*>(yr + 4);
            const float4 q2 = *reinterpret_cast<const float4*>(yr + 8);
            const float4 q3 = *reinterpret_cast<const float4*>(yr + 12);
            const float r_[16] = {q0.x, q0.y, q0.z, q0.w,
                                  q1.x, q1.y, q1.z, q1.w,
                                  q2.x, q2.y, q2.z, q2.w,
                                  q3.x, q3.y, q3.z, q3.w};
            const float xv[VT] = {xq.x, xq.y, xq.z, xq.w};
            #pragma unroll
            for (int k = 0; k < DT; ++k)
                #pragma unroll
                for (int v = 0; v < VT; ++v)
                    acc[k][v] = fmaf(xv[v], r_[12 + v - k], acc[k][v]);
        }

        // write prefetched chunk into the other buffer, then one barrier.
        // Safe: buf[cur^1]'s last readers finished before the previous barrier.
        if (ch + 1 < NCHUNK) {
            #pragma unroll
            for (int kk = 0; kk < NPREF; ++kk) {
                int idx = kk * NTHREADS + t;
                if (idx < YF4) {
                    int r = idx / (YCOLS / 4);
                    int q = idx % (YCOLS / 4);
                    *reinterpret_cast<float4*>(&ysh[cur ^ 1][r][4 * q]) = yp[kk];
                }
            }
            __syncthreads();
        }
    }

    // ---- write out[n, i0+k, h, w0..w0+3] ----
    const size_t ob = ((size_t)(n * D_ + i0) * H_ + h) * W_ + w0;
    #pragma unroll
    for (int k = 0; k < DT; ++k) {
        float4 o;
        o.x = acc[k][0]; o.y = acc[k][1]; o.z = acc[k][2]; o.w = acc[k][3];
        *reinterpret_cast<float4*>(&out[ob + (size_t)k * HW_]) = o;
    }
}

extern "C" void kernel_launch(void* const* d_in, const int* in_sizes, int n_in,
                              void* d_out, int out_size, void* d_ws, size_t ws_size,
                              hipStream_t stream) {
    (void)in_sizes; (void)n_in; (void)out_size; (void)d_ws; (void)ws_size;
    const float* x = (const float*)d_in[0];
    const float* y = (const float*)d_in[1];
    float* out = (float*)d_out;

    dim3 grid(N_ * H_ * (W_ / WTILE));   // 1024 blocks
    dim3 block(NTHREADS);                // 128 threads
    corr1d_v3<<<grid, block, 0, stream>>>(x, y, out);
}

// Round 10
// 197.274 us; speedup vs baseline: 1.4027x; 1.4027x over previous
//
#include <hip/hip_runtime.h>

// x,y [N=4, C=64, H=128, W=256] fp32, maxdisp=48 (fixed by setup_inputs).
// out[n,i,h,w] = sum_c x[n,c,h,w] * y[n,c,h,w-i]; exactly 0 when w < i.
#define N_ 4
#define C_ 64
#define H_ 128
#define W_ 256
#define D_ 48
#define HW_ (H_ * W_)

#define YCOLS 320                // 304 used (48 halo + 256), padded to 320 => 80 f4/row
#define CCHUNK 16
#define NCHUNK (C_ / CCHUNK)     // 4
#define VT 4
#define DT 12
#define NTW (W_ / VT)            // 64 w-threads (one wave)
#define NIG (D_ / DT)            // 4 disparity groups (one per wave)
#define NTHREADS (NTW * NIG)     // 256 = 4 waves
#define YSPW 5                   // y f4-slots per wave: 16*80/64/4
#define XSPW 4                   // x row-slots per wave: 16/4

typedef __attribute__((address_space(3))) void* as3p;
typedef const __attribute__((address_space(1))) void* as1p;

// async global->LDS, 16B per lane; lds base must be wave-uniform (HW adds lane*16)
__device__ __forceinline__ void gl_lds16(const float* g, const float* l) {
    __builtin_amdgcn_global_load_lds((as1p)(const void*)g, (as3p)(void*)l, 16, 0, 0);
}

// LDS: (16*320 + 16*256)*4 = 36864 B per buffer, x2 = 73728 B -> 2 blocks/CU.
// Grid 512 = N*H, one block per (n,h) row; 2 blocks/CU exact.
__global__ __launch_bounds__(NTHREADS, 2)
void corr1d_v4(const float* __restrict__ x,
               const float* __restrict__ y,
               float* __restrict__ out) {
    __shared__ __align__(16) float ysh[2][CCHUNK][YCOLS];
    __shared__ __align__(16) float xsh[2][CCHUNK][W_];

    const int t    = threadIdx.x;
    const int lane = t & 63;
    const int wv   = t >> 6;      // wave 0..3
    const int tw   = lane;        // w-thread 0..63 (w0 = 4*tw)
    const int ig   = wv;          // disparity group (i0 = 12*ig)
    const int nh   = blockIdx.x;
    const int n    = nh / H_;
    const int h    = nh % H_;
    const size_t in_base = ((size_t)n * C_ * H_ + h) * W_;

    // ---- per-slot y staging precompute (static-indexed arrays -> registers) ----
    // f4 slot idx in [0,1280): row = idx/80, q = idx%80, global w = clamp(4q-48, 0, 252).
    // Clamped cols (q<12) hold garbage; their outputs are masked to 0 at the store.
    int yrow[YSPW], ywoff[YSPW];
    #pragma unroll
    for (int s = 0; s < YSPW; ++s) {
        int idx = (wv * YSPW + s) * 64 + lane;
        int r = idx / 80;
        int q = idx - r * 80;
        int w = 4 * q - D_;
        if (w < 0) w = 0;
        if (w > W_ - 4) w = W_ - 4;
        yrow[s] = r;
        ywoff[s] = w;
    }

    float* yflat = &ysh[0][0][0];

    // window: ysh col j = 48 + 4*tw + v - 12*ig - k; aligned start js; m = 12+v-k in [1,15]
    const int js = 4 * tw - DT * ig + (D_ - DT);   // 0..288

    float acc[DT][VT];
    #pragma unroll
    for (int k = 0; k < DT; ++k)
        #pragma unroll
        for (int v = 0; v < VT; ++v) acc[k][v] = 0.f;

    // ---- async stage of chunk c0 into buffer `buf` ----
    auto stage = [&](int buf, int c0) {
        #pragma unroll
        for (int s = 0; s < YSPW; ++s) {
            const float* g = y + in_base + (size_t)(c0 + yrow[s]) * HW_ + ywoff[s];
            const float* l = yflat + (size_t)buf * (CCHUNK * YCOLS)
                                   + (wv * YSPW + s) * 256;   // 64 lanes * 4 floats
            gl_lds16(g, l);
        }
        #pragma unroll
        for (int s = 0; s < XSPW; ++s) {
            int r = wv * XSPW + s;                            // one x row per slot
            const float* g = x + in_base + (size_t)(c0 + r) * HW_ + 4 * lane;
            const float* l = &xsh[buf][r][0];
            gl_lds16(g, l);
        }
    };

    stage(0, 0);
    __syncthreads();                 // drains vmcnt -> buf0 ready

    for (int ch = 0; ch < NCHUNK; ++ch) {
        const int cur = ch & 1;
        if (ch + 1 < NCHUNK) stage(cur ^ 1, (ch + 1) * CCHUNK);   // async, flies under compute

        #pragma unroll
        for (int cc = 0; cc < CCHUNK; ++cc) {
            const float* yr = &ysh[cur][cc][js];
            const float4 q0 = *reinterpret_cast<const float4*>(yr);
            const float4 q1 = *reinterpret_cast<const float4*>(yr + 4);
            const float4 q2 = *reinterpret_cast<const float4*>(yr + 8);
            const float4 q3 = *reinterpret_cast<const float4*>(yr + 12);
            const float4 xq = *reinterpret_cast<const float4*>(&xsh[cur][cc][4 * tw]);
            const float r_[16] = {q0.x, q0.y, q0.z, q0.w,
                                  q1.x, q1.y, q1.z, q1.w,
                                  q2.x, q2.y, q2.z, q2.w,
                                  q3.x, q3.y, q3.z, q3.w};
            const float xv[VT] = {xq.x, xq.y, xq.z, xq.w};
            #pragma unroll
            for (int k = 0; k < DT; ++k)
                #pragma unroll
                for (int v = 0; v < VT; ++v)
                    acc[k][v] = fmaf(xv[v], r_[12 + v - k], acc[k][v]);
        }
        if (ch + 1 < NCHUNK) __syncthreads();   // drains next-chunk loads; swap
    }

    // ---- store out[n, 12*ig+k, h, 4*tw+v]; mask w<i outputs to exact 0 ----
    const size_t ob = ((size_t)(n * D_ + ig * DT) * H_ + h) * W_ + 4 * tw;
    #pragma unroll
    for (int k = 0; k < DT; ++k) {
        const int ik = ig * DT + k;
        float4 o;
        o.x = (4 * tw + 0 >= ik) ? acc[k][0] : 0.f;
        o.y = (4 * tw + 1 >= ik) ? acc[k][1] : 0.f;
        o.z = (4 * tw + 2 >= ik) ? acc[k][2] : 0.f;
        o.w = (4 * tw + 3 >= ik) ? acc[k][3] : 0.f;
        *reinterpret_cast<float4*>(&out[ob + (size_t)k * HW_]) = o;
    }
}

extern "C" void kernel_launch(void* const* d_in, const int* in_sizes, int n_in,
                              void* d_out, int out_size, void* d_ws, size_t ws_size,
                              hipStream_t stream) {
    (void)in_sizes; (void)n_in; (void)out_size; (void)d_ws; (void)ws_size;
    const float* x = (const float*)d_in[0];
    const float* y = (const float*)d_in[1];
    float* out = (float*)d_out;

    dim3 grid(N_ * H_);       // 512 blocks, one per (n,h) row
    dim3 block(NTHREADS);     // 256 threads = 4 waves
    corr1d_v4<<<grid, block, 0, stream>>>(x, y, out);
}

// Round 13
// 131.639 us; speedup vs baseline: 2.1021x; 1.4986x over previous
//
#include <hip/hip_runtime.h>

// x,y [N=4, C=64, H=128, W=256] fp32, maxdisp=48 (fixed by setup_inputs).
// out[n,i,h,w] = sum_c x[n,c,h,w] * y[n,c,h,w-i]; exactly 0 when w < i.
#define N_ 4
#define C_ 64
#define H_ 128
#define W_ 256
#define D_ 48
#define HW_ (H_ * W_)

#define YCOLS 320                // 304 used (48 halo + 256), padded to 320 => 80 f4/row
#define CCHUNK 16
#define NCHUNK (C_ / CCHUNK)     // 4
#define VT 4
#define DT 12
#define NTW (W_ / VT)            // 64 w-threads (one wave)
#define NIG (D_ / DT)            // 4 disparity groups (one per wave)
#define NTHREADS (NTW * NIG)     // 256 = 4 waves
#define YSPW 5                   // y f4-slots per wave: 16*80/64/4
#define XSPW 4                   // x row-slots per wave: 16/4

typedef __attribute__((address_space(3))) void* as3p;
typedef const __attribute__((address_space(1))) void* as1p;

// async global->LDS, 16B per lane; lds base must be wave-uniform (HW adds lane*16)
__device__ __forceinline__ void gl_lds16(const float* g, const float* l) {
    __builtin_amdgcn_global_load_lds((as1p)(const void*)g, (as3p)(void*)l, 16, 0, 0);
}

// LDS: (16*320 + 16*256)*4 = 36864 B per buffer, x2 = 73728 B -> 2 blocks/CU.
// Grid 512 = N*H, one block per (n,h) row; 2 blocks/CU exact (8 waves/CU).
// launch_bounds min-waves=1: do NOT let the compiler cap VGPRs at 128 —
// v3/v4 both hit exactly 128 + ~220 MB scratch writes with (_,2).
__global__ __launch_bounds__(NTHREADS, 1)
void corr1d_v5(const float* __restrict__ x,
               const float* __restrict__ y,
               float* __restrict__ out) {
    __shared__ __align__(16) float ysh[2][CCHUNK][YCOLS];
    __shared__ __align__(16) float xsh[2][CCHUNK][W_];

    const int t    = threadIdx.x;
    const int lane = t & 63;
    const int wv   = t >> 6;      // wave 0..3
    const int tw   = lane;        // w-thread 0..63 (w0 = 4*tw)
    const int ig   = wv;          // disparity group (i0 = 12*ig)
    const int nh   = blockIdx.x;
    const int n    = nh / H_;
    const int h    = nh % H_;
    const size_t in_base = ((size_t)n * C_ * H_ + h) * W_;

    float* yflat = &ysh[0][0][0];

    // window: ysh col j = 48 + 4*tw + v - 12*ig - k; aligned start js; m = 12+v-k in [1,15]
    const int js = 4 * tw - DT * ig + (D_ - DT);   // 0..288

    float acc[DT][VT];
    #pragma unroll
    for (int k = 0; k < DT; ++k)
        #pragma unroll
        for (int v = 0; v < VT; ++v) acc[k][v] = 0.f;

    // ---- async stage of chunk c0 into buffer `buf` ----
    // y f4-slot idx in [0,1280): row = idx/80, q = idx%80,
    // global w = clamp(4q-48, 0, 252). Clamped cols (q<12) hold garbage; those
    // feed only outputs masked to exact 0 (w<i) at the store. Addresses are
    // recomputed inline each call (no persistent arrays -> no register drag).
    auto stage = [&](int buf, int c0) {
        #pragma unroll
        for (int s = 0; s < YSPW; ++s) {
            int idx = (wv * YSPW + s) * 64 + lane;
            int r = idx / 80;
            int q = idx - r * 80;
            int w = 4 * q - D_;
            if (w < 0) w = 0;
            if (w > W_ - 4) w = W_ - 4;
            const float* g = y + in_base + (size_t)(c0 + r) * HW_ + w;
            const float* l = yflat + (size_t)buf * (CCHUNK * YCOLS)
                                   + (wv * YSPW + s) * 256;   // 64 lanes * 4 floats
            gl_lds16(g, l);
        }
        #pragma unroll
        for (int s = 0; s < XSPW; ++s) {
            int r = wv * XSPW + s;                            // one x row per slot
            const float* g = x + in_base + (size_t)(c0 + r) * HW_ + 4 * lane;
            const float* l = &xsh[buf][r][0];
            gl_lds16(g, l);
        }
    };

    stage(0, 0);
    __syncthreads();                 // drains vmcnt -> buf0 ready

    for (int ch = 0; ch < NCHUNK; ++ch) {
        const int cur = ch & 1;
        if (ch + 1 < NCHUNK) stage(cur ^ 1, (ch + 1) * CCHUNK);   // async, flies under compute

        #pragma unroll
        for (int cc = 0; cc < CCHUNK; ++cc) {
            const float* yr = &ysh[cur][cc][js];
            const float4 q0 = *reinterpret_cast<const float4*>(yr);
            const float4 q1 = *reinterpret_cast<const float4*>(yr + 4);
            const float4 q2 = *reinterpret_cast<const float4*>(yr + 8);
            const float4 q3 = *reinterpret_cast<const float4*>(yr + 12);
            const float4 xq = *reinterpret_cast<const float4*>(&xsh[cur][cc][4 * tw]);
            const float r_[16] = {q0.x, q0.y, q0.z, q0.w,
                                  q1.x, q1.y, q1.z, q1.w,
                                  q2.x, q2.y, q2.z, q2.w,
                                  q3.x, q3.y, q3.z, q3.w};
            const float xv[VT] = {xq.x, xq.y, xq.z, xq.w};
            #pragma unroll
            for (int k = 0; k < DT; ++k)
                #pragma unroll
                for (int v = 0; v < VT; ++v)
                    acc[k][v] = fmaf(xv[v], r_[12 + v - k], acc[k][v]);
        }
        if (ch + 1 < NCHUNK) __syncthreads();   // drains next-chunk loads; swap
    }

    // ---- store out[n, 12*ig+k, h, 4*tw+v]; mask w<i outputs to exact 0 ----
    const size_t ob = ((size_t)(n * D_ + ig * DT) * H_ + h) * W_ + 4 * tw;
    #pragma unroll
    for (int k = 0; k < DT; ++k) {
        const int ik = ig * DT + k;
        float4 o;
        o.x = (4 * tw + 0 >= ik) ? acc[k][0] : 0.f;
        o.y = (4 * tw + 1 >= ik) ? acc[k][1] : 0.f;
        o.z = (4 * tw + 2 >= ik) ? acc[k][2] : 0.f;
        o.w = (4 * tw + 3 >= ik) ? acc[k][3] : 0.f;
        *reinterpret_cast<float4*>(&out[ob + (size_t)k * HW_]) = o;
    }
}

extern "C" void kernel_launch(void* const* d_in, const int* in_sizes, int n_in,
                              void* d_out, int out_size, void* d_ws, size_t ws_size,
                              hipStream_t stream) {
    (void)in_sizes; (void)n_in; (void)out_size; (void)d_ws; (void)ws_size;
    const float* x = (const float*)d_in[0];
    const float* y = (const float*)d_in[1];
    float* out = (float*)d_out;

    dim3 grid(N_ * H_);       // 512 blocks, one per (n,h) row
    dim3 block(NTHREADS);     // 256 threads = 4 waves
    corr1d_v5<<<grid, block, 0, stream>>>(x, y, out);
}